// Round 1
// baseline (61.376 us; speedup 1.0000x reference)
//
#include <hip/hip_runtime.h>

// TrafficNetworkDQN fused forward, fp32.
// B=4096, L=256 -> 1,048,576 positions, one thread per position.
// Heads' first-layer signal contribution is precomputed per block into LDS
// (only 8 distinct signal states) -- saves 512 FMAs/position (22%).

#define BL_TOTAL (4096 * 256)

__global__ __launch_bounds__(256) void dqn_fused(
    const float* __restrict__ lf,    // [BL,5]
    const int*   __restrict__ ss,    // [BL]
    const float* __restrict__ le_w1, const float* __restrict__ le_b1,   // 5x16, 16
    const float* __restrict__ le_w2, const float* __restrict__ le_b2,   // 16x8, 8
    const float* __restrict__ emb,                                      // 8x8
    const float* __restrict__ ls_w1, const float* __restrict__ ls_b1,   // 16x32, 32
    const float* __restrict__ ls_w2, const float* __restrict__ ls_b2,   // 32x16, 16
    const float* __restrict__ ls_w3, const float* __restrict__ ls_b3,   // 16x1, 1
    const float* __restrict__ as_w1, const float* __restrict__ as_b1,   // 16x32, 32
    const float* __restrict__ as_w2, const float* __restrict__ as_b2,   // 32x16, 16
    const float* __restrict__ as_w3, const float* __restrict__ as_b3,   // 16x2, 2
    float* __restrict__ out)         // [BL] scores then [BL,2] action values
{
    // contrib[head][k][s] = b1[k] + sum_j emb[s][j] * w1[8+j][k]
    // [k][s] layout: divergent s -> 8 consecutive dwords -> no bank conflict.
    __shared__ float contrib[2][32][8];

    const int t = threadIdx.x;
    #pragma unroll
    for (int i = 0; i < 2; ++i) {
        const int idx  = t + i * 256;            // 0..511
        const int head = idx >> 8;
        const int k    = (idx >> 3) & 31;
        const int s    = idx & 7;
        const float* w1 = head ? as_w1 : ls_w1;
        const float* b1 = head ? as_b1 : ls_b1;
        float a = b1[k];
        #pragma unroll
        for (int j = 0; j < 8; ++j)
            a = fmaf(emb[s * 8 + j], w1[(8 + j) * 32 + k], a);
        contrib[head][k][s] = a;
    }
    __syncthreads();

    const int pos = blockIdx.x * 256 + t;
    if (pos >= BL_TOTAL) return;

    // ---- inputs ----
    float f[5];
    #pragma unroll
    for (int j = 0; j < 5; ++j) f[j] = lf[pos * 5 + j];
    const int s = ss[pos];

    // ---- link encoder: 5 -> 16 -> 8 (relu, relu) ----
    float h[16];
    #pragma unroll
    for (int k = 0; k < 16; ++k) {
        float a = le_b1[k];
        #pragma unroll
        for (int j = 0; j < 5; ++j) a = fmaf(f[j], le_w1[j * 16 + k], a);
        h[k] = fmaxf(a, 0.0f);
    }
    float e[8];
    #pragma unroll
    for (int k = 0; k < 8; ++k) {
        float a = le_b2[k];
        #pragma unroll
        for (int j = 0; j < 16; ++j) a = fmaf(h[j], le_w2[j * 8 + k], a);
        e[k] = fmaxf(a, 0.0f);
    }

    // ---- link-selector head: 16 -> 32 -> 16 -> 1 ----
    float g[32];
    #pragma unroll
    for (int k = 0; k < 32; ++k) {
        float a = contrib[0][k][s];
        #pragma unroll
        for (int j = 0; j < 8; ++j) a = fmaf(e[j], ls_w1[j * 32 + k], a);
        g[k] = fmaxf(a, 0.0f);
    }
    float h2[16];
    #pragma unroll
    for (int k = 0; k < 16; ++k) {
        float a = ls_b2[k];
        #pragma unroll
        for (int j = 0; j < 32; ++j) a = fmaf(g[j], ls_w2[j * 16 + k], a);
        h2[k] = fmaxf(a, 0.0f);
    }
    float score = ls_b3[0];
    #pragma unroll
    for (int j = 0; j < 16; ++j) score = fmaf(h2[j], ls_w3[j], score);
    out[pos] = score;

    // ---- action-selector head: 16 -> 32 -> 16 -> 2 (reuse g, h2) ----
    #pragma unroll
    for (int k = 0; k < 32; ++k) {
        float a = contrib[1][k][s];
        #pragma unroll
        for (int j = 0; j < 8; ++j) a = fmaf(e[j], as_w1[j * 32 + k], a);
        g[k] = fmaxf(a, 0.0f);
    }
    #pragma unroll
    for (int k = 0; k < 16; ++k) {
        float a = as_b2[k];
        #pragma unroll
        for (int j = 0; j < 32; ++j) a = fmaf(g[j], as_w2[j * 16 + k], a);
        h2[k] = fmaxf(a, 0.0f);
    }
    float a0 = as_b3[0];
    float a1 = as_b3[1];
    #pragma unroll
    for (int j = 0; j < 16; ++j) {
        a0 = fmaf(h2[j], as_w3[j * 2 + 0], a0);
        a1 = fmaf(h2[j], as_w3[j * 2 + 1], a1);
    }
    *reinterpret_cast<float2*>(&out[BL_TOTAL + 2 * pos]) = make_float2(a0, a1);
}

extern "C" void kernel_launch(void* const* d_in, const int* in_sizes, int n_in,
                              void* d_out, int out_size, void* d_ws, size_t ws_size,
                              hipStream_t stream) {
    const float* lf    = (const float*)d_in[0];
    const int*   ss    = (const int*)  d_in[1];
    const float* le_w1 = (const float*)d_in[2];
    const float* le_b1 = (const float*)d_in[3];
    const float* le_w2 = (const float*)d_in[4];
    const float* le_b2 = (const float*)d_in[5];
    const float* emb   = (const float*)d_in[6];
    const float* ls_w1 = (const float*)d_in[7];
    const float* ls_b1 = (const float*)d_in[8];
    const float* ls_w2 = (const float*)d_in[9];
    const float* ls_b2 = (const float*)d_in[10];
    const float* ls_w3 = (const float*)d_in[11];
    const float* ls_b3 = (const float*)d_in[12];
    const float* as_w1 = (const float*)d_in[13];
    const float* as_b1 = (const float*)d_in[14];
    const float* as_w2 = (const float*)d_in[15];
    const float* as_b2 = (const float*)d_in[16];
    const float* as_w3 = (const float*)d_in[17];
    const float* as_b3 = (const float*)d_in[18];
    float* out = (float*)d_out;

    dqn_fused<<<BL_TOTAL / 256, 256, 0, stream>>>(
        lf, ss, le_w1, le_b1, le_w2, le_b2, emb,
        ls_w1, ls_b1, ls_w2, ls_b2, ls_w3, ls_b3,
        as_w1, as_b1, as_w2, as_b2, as_w3, as_b3,
        out);
}

// Round 3
// 34.119 us; speedup vs baseline: 1.7989x; 1.7989x over previous
//
#include <hip/hip_runtime.h>

// TrafficNetworkDQN fused forward via fp16 MFMA (gfx950).
//
// All layers computed TRANSPOSED:  Act_out[n, m] = W^T[n,k] @ Act_in[k, m] + b[n]
// with positions m on the MFMA *N* dimension. Then the C/D fragment layout
// (col = lane&15 = m, row = 4*(lane>>4)+reg = n) is identical to the next
// layer's B fragment layout (col = lane&15 = m, k = 4*(lane>>4)+elem), so a
// layer transition is just relu + cvt in-lane: NO LDS, NO shuffles.
// Weights live as per-lane A-fragments (loaded once per wave); biases are
// folded in as the MFMA C-in. K=32 layers are split into two chained K=16
// MFMAs so the reg<->elem mapping holds everywhere.
//
// Layers (per 16-position tile, 12 MFMAs):
//  L1: X[5->16]   1 MFMA   (K padded 5->16)
//  L2: H1[16->8]  1 MFMA   (rows 8..15 zero; lanes g>=2 replaced by emb[s])
//  L3: C[16->64]  4 MFMAs  (both heads' W1 concatenated along n)
//  L4: G[32->16]x2 heads   4 MFMAs (K split 16+16)
//  L5: H2[32->3]  2 MFMAs  (block-diag [ls_w3 | as_w3], N padded 3->16)

#define BL_TOTAL (4096 * 256)

typedef _Float16 half4  __attribute__((ext_vector_type(4)));
typedef __fp16   fp16x2 __attribute__((ext_vector_type(2)));
typedef float    floatx4 __attribute__((ext_vector_type(4)));

#define MFMA16(A, B, C) __builtin_amdgcn_mfma_f32_16x16x16f16((A), (B), (C), 0, 0, 0)

static __device__ __forceinline__ half4 relu_pack(floatx4 c) {
    float a0 = fmaxf(c[0], 0.0f), a1 = fmaxf(c[1], 0.0f);
    float a2 = fmaxf(c[2], 0.0f), a3 = fmaxf(c[3], 0.0f);
    fp16x2 lo = __builtin_amdgcn_cvt_pkrtz(a0, a1);
    fp16x2 hi = __builtin_amdgcn_cvt_pkrtz(a2, a3);
    half4 r;
    r[0] = (_Float16)lo[0]; r[1] = (_Float16)lo[1];
    r[2] = (_Float16)hi[0]; r[3] = (_Float16)hi[1];
    return r;
}

static __device__ __forceinline__ half4 pack4_rne(float a, float b, float c, float d) {
    half4 r; r[0] = (_Float16)a; r[1] = (_Float16)b; r[2] = (_Float16)c; r[3] = (_Float16)d;
    return r;
}

__global__ __launch_bounds__(256, 4) void dqn_mfma(
    const float* __restrict__ lf,    // [BL,5]
    const int*   __restrict__ ss,    // [BL]
    const float* __restrict__ le_w1, const float* __restrict__ le_b1,   // 5x16, 16
    const float* __restrict__ le_w2, const float* __restrict__ le_b2,   // 16x8, 8
    const float* __restrict__ emb,                                      // 8x8
    const float* __restrict__ ls_w1, const float* __restrict__ ls_b1,   // 16x32, 32
    const float* __restrict__ ls_w2, const float* __restrict__ ls_b2,   // 32x16, 16
    const float* __restrict__ ls_w3, const float* __restrict__ ls_b3,   // 16x1, 1
    const float* __restrict__ as_w1, const float* __restrict__ as_b1,   // 16x32, 32
    const float* __restrict__ as_w2, const float* __restrict__ as_b2,   // 32x16, 16
    const float* __restrict__ as_w3, const float* __restrict__ as_b3,   // 16x2, 2
    float* __restrict__ out)         // [BL] scores, then [BL,2] action values
{
    const int lane = threadIdx.x & 63;
    const int wave = threadIdx.x >> 6;
    const int m16  = lane & 15;   // position within tile (N dim) / n_out for A frags
    const int g    = lane >> 4;   // lane group 0..3
    const int k0   = g * 4;       // base k index of this lane's 4 fragment elems

    // ---- stage emb table to LDS as fp16 [8][8] ----
    __shared__ _Float16 embLDS[64];
    if (threadIdx.x < 64) embLDS[threadIdx.x] = (_Float16)emb[threadIdx.x];
    __syncthreads();

    // ---- A fragments: A[n_out=m16][k=k0+j] = W[k][n_out] (zero-padded) ----
    half4 a1 = pack4_rne(
        (k0 + 0 < 5) ? le_w1[(k0 + 0) * 16 + m16] : 0.0f,
        (k0 + 1 < 5) ? le_w1[(k0 + 1) * 16 + m16] : 0.0f,
        (k0 + 2 < 5) ? le_w1[(k0 + 2) * 16 + m16] : 0.0f,
        (k0 + 3 < 5) ? le_w1[(k0 + 3) * 16 + m16] : 0.0f);
    half4 a2 = pack4_rne(
        (m16 < 8) ? le_w2[(k0 + 0) * 8 + m16] : 0.0f,
        (m16 < 8) ? le_w2[(k0 + 1) * 8 + m16] : 0.0f,
        (m16 < 8) ? le_w2[(k0 + 2) * 8 + m16] : 0.0f,
        (m16 < 8) ? le_w2[(k0 + 3) * 8 + m16] : 0.0f);
    half4 a3_0 = pack4_rne(ls_w1[(k0+0)*32 + m16],      ls_w1[(k0+1)*32 + m16],
                           ls_w1[(k0+2)*32 + m16],      ls_w1[(k0+3)*32 + m16]);
    half4 a3_1 = pack4_rne(ls_w1[(k0+0)*32 + 16 + m16], ls_w1[(k0+1)*32 + 16 + m16],
                           ls_w1[(k0+2)*32 + 16 + m16], ls_w1[(k0+3)*32 + 16 + m16]);
    half4 a3_2 = pack4_rne(as_w1[(k0+0)*32 + m16],      as_w1[(k0+1)*32 + m16],
                           as_w1[(k0+2)*32 + m16],      as_w1[(k0+3)*32 + m16]);
    half4 a3_3 = pack4_rne(as_w1[(k0+0)*32 + 16 + m16], as_w1[(k0+1)*32 + 16 + m16],
                           as_w1[(k0+2)*32 + 16 + m16], as_w1[(k0+3)*32 + 16 + m16]);
    half4 a4ls0 = pack4_rne(ls_w2[(k0+0)*16 + m16],      ls_w2[(k0+1)*16 + m16],
                            ls_w2[(k0+2)*16 + m16],      ls_w2[(k0+3)*16 + m16]);
    half4 a4ls1 = pack4_rne(ls_w2[(16+k0+0)*16 + m16],   ls_w2[(16+k0+1)*16 + m16],
                            ls_w2[(16+k0+2)*16 + m16],   ls_w2[(16+k0+3)*16 + m16]);
    half4 a4as0 = pack4_rne(as_w2[(k0+0)*16 + m16],      as_w2[(k0+1)*16 + m16],
                            as_w2[(k0+2)*16 + m16],      as_w2[(k0+3)*16 + m16]);
    half4 a4as1 = pack4_rne(as_w2[(16+k0+0)*16 + m16],   as_w2[(16+k0+1)*16 + m16],
                            as_w2[(16+k0+2)*16 + m16],   as_w2[(16+k0+3)*16 + m16]);
    half4 a5a = pack4_rne(
        (m16 == 0) ? ls_w3[k0 + 0] : 0.0f,
        (m16 == 0) ? ls_w3[k0 + 1] : 0.0f,
        (m16 == 0) ? ls_w3[k0 + 2] : 0.0f,
        (m16 == 0) ? ls_w3[k0 + 3] : 0.0f);
    half4 a5b = pack4_rne(
        (m16 == 1) ? as_w3[(k0+0)*2] : ((m16 == 2) ? as_w3[(k0+0)*2 + 1] : 0.0f),
        (m16 == 1) ? as_w3[(k0+1)*2] : ((m16 == 2) ? as_w3[(k0+1)*2 + 1] : 0.0f),
        (m16 == 1) ? as_w3[(k0+2)*2] : ((m16 == 2) ? as_w3[(k0+2)*2 + 1] : 0.0f),
        (m16 == 1) ? as_w3[(k0+3)*2] : ((m16 == 2) ? as_w3[(k0+3)*2 + 1] : 0.0f));

    // ---- bias fragments: C-in, reg r -> n_out = 4*g + r ----
    const int n0 = 4 * g;
    floatx4 bias1, bias2, bias3_0, bias3_1, bias3_2, bias3_3, bias4ls, bias4as, bias5;
    #pragma unroll
    for (int r = 0; r < 4; ++r) {
        bias1[r]   = le_b1[n0 + r];
        bias2[r]   = (n0 + r < 8) ? le_b2[n0 + r] : 0.0f;
        bias3_0[r] = ls_b1[n0 + r];
        bias3_1[r] = ls_b1[16 + n0 + r];
        bias3_2[r] = as_b1[n0 + r];
        bias3_3[r] = as_b1[16 + n0 + r];
        bias4ls[r] = ls_b2[n0 + r];
        bias4as[r] = as_b2[n0 + r];
        bias5[r]   = 0.0f;
    }
    if (g == 0) { bias5[0] = ls_b3[0]; bias5[1] = as_b3[0]; bias5[2] = as_b3[1]; }

    // ---- main loop: 8 tiles of 16 positions per wave ----
    const int tile0 = blockIdx.x * 32 + wave * 8;
    float* __restrict__ out2 = out + BL_TOTAL;

    for (int t = 0; t < 8; ++t) {
        const int pos = (tile0 + t) * 16 + m16;

        // B1: X[k][m], k = k0+j (valid k<5)
        float x0 = 0.0f, x1 = 0.0f, x2 = 0.0f, x3 = 0.0f;
        if (g == 0) {
            x0 = lf[pos * 5 + 0]; x1 = lf[pos * 5 + 1];
            x2 = lf[pos * 5 + 2]; x3 = lf[pos * 5 + 3];
        } else if (g == 1) {
            x0 = lf[pos * 5 + 4];
        }
        const int s = ss[pos];
        half4 b1 = pack4_rne(x0, x1, x2, x3);

        floatx4 c1 = MFMA16(a1, b1, bias1);            // H1 [16, m]
        half4 bh1 = relu_pack(c1);

        floatx4 c2 = MFMA16(a2, bh1, bias2);           // E [8, m] (rows 8..15 = 0)

        // B3: k<8 from E (lane groups 0,1), k>=8 from emb[s] (groups 2,3)
        half4 b3 = relu_pack(c2);
        half4 ev = *reinterpret_cast<const half4*>(&embLDS[s * 8 + (g & 1) * 4]);
        if (g >= 2) b3 = ev;

        floatx4 c30 = MFMA16(a3_0, b3, bias3_0);       // G rows  0..15
        floatx4 c31 = MFMA16(a3_1, b3, bias3_1);       // G rows 16..31
        floatx4 c32 = MFMA16(a3_2, b3, bias3_2);       // G rows 32..47
        floatx4 c33 = MFMA16(a3_3, b3, bias3_3);       // G rows 48..63
        half4 g0 = relu_pack(c30), g1 = relu_pack(c31);
        half4 g2 = relu_pack(c32), g3 = relu_pack(c33);

        floatx4 cls = MFMA16(a4ls1, g1, MFMA16(a4ls0, g0, bias4ls));  // H2ls [16,m]
        floatx4 cas = MFMA16(a4as1, g3, MFMA16(a4as0, g2, bias4as));  // H2as [16,m]
        half4 hls = relu_pack(cls), has = relu_pack(cas);

        floatx4 c5 = MFMA16(a5b, has, MFMA16(a5a, hls, bias5));
        // c5: lane group 0 holds n=0 (score), n=1 (av0), n=2 (av1) for position m16
        if (g == 0) {
            out[pos] = c5[0];
            reinterpret_cast<float2*>(out2)[pos] = make_float2(c5[1], c5[2]);
        }
    }
}

extern "C" void kernel_launch(void* const* d_in, const int* in_sizes, int n_in,
                              void* d_out, int out_size, void* d_ws, size_t ws_size,
                              hipStream_t stream) {
    const float* lf    = (const float*)d_in[0];
    const int*   ss    = (const int*)  d_in[1];
    const float* le_w1 = (const float*)d_in[2];
    const float* le_b1 = (const float*)d_in[3];
    const float* le_w2 = (const float*)d_in[4];
    const float* le_b2 = (const float*)d_in[5];
    const float* emb   = (const float*)d_in[6];
    const float* ls_w1 = (const float*)d_in[7];
    const float* ls_b1 = (const float*)d_in[8];
    const float* ls_w2 = (const float*)d_in[9];
    const float* ls_b2 = (const float*)d_in[10];
    const float* ls_w3 = (const float*)d_in[11];
    const float* ls_b3 = (const float*)d_in[12];
    const float* as_w1 = (const float*)d_in[13];
    const float* as_b1 = (const float*)d_in[14];
    const float* as_w2 = (const float*)d_in[15];
    const float* as_b2 = (const float*)d_in[16];
    const float* as_w3 = (const float*)d_in[17];
    const float* as_b3 = (const float*)d_in[18];
    float* out = (float*)d_out;

    // 2048 blocks x 4 waves x 8 tiles x 16 positions = 1,048,576
    dqn_mfma<<<2048, 256, 0, stream>>>(
        lf, ss, le_w1, le_b1, le_w2, le_b2, emb,
        ls_w1, ls_b1, ls_w2, ls_b2, ls_w3, ls_b3,
        as_w1, as_b1, as_w2, as_b2, as_w3, as_b3,
        out);
}

// Round 5
// 29.190 us; speedup vs baseline: 2.1026x; 1.1688x over previous
//
#include <hip/hip_runtime.h>

// TrafficNetworkDQN fused forward via fp16 MFMA (gfx950).
//
// All layers computed TRANSPOSED:  Act_out[n, m] = W^T[n,k] @ Act_in[k, m] + b[n]
// with positions m on the MFMA *N* dimension: the C/D fragment layout
// (col = lane&15 = m, row = 4*(lane>>4)+reg = n) equals the next layer's
// B fragment layout, so layer transitions are in-lane relu+cvt only.
// R5: R3's proven arithmetic (fmaxf + cvt_pkrtz relu, RNE input pack)
// + 2-way tile interleave only (two independent MFMA chains per iteration,
// attacking the serial-chain latency bound: R3 showed MfmaUtil 10.7 /
// VALUBusy 28 / occupancy 34 -- all pipes idle on one dep chain).

#define BL_TOTAL (4096 * 256)

typedef _Float16 half4   __attribute__((ext_vector_type(4)));
typedef __fp16   fp16x2  __attribute__((ext_vector_type(2)));
typedef float    floatx4 __attribute__((ext_vector_type(4)));

#define MFMA16(A, B, C) __builtin_amdgcn_mfma_f32_16x16x16f16((A), (B), (C), 0, 0, 0)

static __device__ __forceinline__ half4 relu_pack(floatx4 c) {
    float a0 = fmaxf(c[0], 0.0f), a1 = fmaxf(c[1], 0.0f);
    float a2 = fmaxf(c[2], 0.0f), a3 = fmaxf(c[3], 0.0f);
    fp16x2 lo = __builtin_amdgcn_cvt_pkrtz(a0, a1);
    fp16x2 hi = __builtin_amdgcn_cvt_pkrtz(a2, a3);
    half4 r;
    r[0] = (_Float16)lo[0]; r[1] = (_Float16)lo[1];
    r[2] = (_Float16)hi[0]; r[3] = (_Float16)hi[1];
    return r;
}

static __device__ __forceinline__ half4 pack4_rne(float a, float b, float c, float d) {
    half4 r; r[0] = (_Float16)a; r[1] = (_Float16)b; r[2] = (_Float16)c; r[3] = (_Float16)d;
    return r;
}

__global__ __launch_bounds__(256, 4) void dqn_mfma(
    const float* __restrict__ lf,    // [BL,5]
    const int*   __restrict__ ss,    // [BL]
    const float* __restrict__ le_w1, const float* __restrict__ le_b1,   // 5x16, 16
    const float* __restrict__ le_w2, const float* __restrict__ le_b2,   // 16x8, 8
    const float* __restrict__ emb,                                      // 8x8
    const float* __restrict__ ls_w1, const float* __restrict__ ls_b1,   // 16x32, 32
    const float* __restrict__ ls_w2, const float* __restrict__ ls_b2,   // 32x16, 16
    const float* __restrict__ ls_w3, const float* __restrict__ ls_b3,   // 16x1, 1
    const float* __restrict__ as_w1, const float* __restrict__ as_b1,   // 16x32, 32
    const float* __restrict__ as_w2, const float* __restrict__ as_b2,   // 32x16, 16
    const float* __restrict__ as_w3, const float* __restrict__ as_b3,   // 16x2, 2
    float* __restrict__ out)         // [BL] scores, then [BL,2] action values
{
    const int lane = threadIdx.x & 63;
    const int wave = threadIdx.x >> 6;
    const int m16  = lane & 15;   // position within tile (N dim) / n_out for A frags
    const int g    = lane >> 4;   // lane group 0..3
    const int k0   = g * 4;       // base k index of this lane's 4 fragment elems

    // ---- stage emb table to LDS as fp16 [8][8] ----
    __shared__ _Float16 embLDS[64];
    if (threadIdx.x < 64) embLDS[threadIdx.x] = (_Float16)emb[threadIdx.x];
    __syncthreads();

    // ---- A fragments: A[n_out=m16][k=k0+j] = W[k][n_out] (zero-padded) ----
    half4 a1 = pack4_rne(
        (k0 + 0 < 5) ? le_w1[(k0 + 0) * 16 + m16] : 0.0f,
        (k0 + 1 < 5) ? le_w1[(k0 + 1) * 16 + m16] : 0.0f,
        (k0 + 2 < 5) ? le_w1[(k0 + 2) * 16 + m16] : 0.0f,
        (k0 + 3 < 5) ? le_w1[(k0 + 3) * 16 + m16] : 0.0f);
    half4 a2 = pack4_rne(
        (m16 < 8) ? le_w2[(k0 + 0) * 8 + m16] : 0.0f,
        (m16 < 8) ? le_w2[(k0 + 1) * 8 + m16] : 0.0f,
        (m16 < 8) ? le_w2[(k0 + 2) * 8 + m16] : 0.0f,
        (m16 < 8) ? le_w2[(k0 + 3) * 8 + m16] : 0.0f);
    half4 a3_0 = pack4_rne(ls_w1[(k0+0)*32 + m16],      ls_w1[(k0+1)*32 + m16],
                           ls_w1[(k0+2)*32 + m16],      ls_w1[(k0+3)*32 + m16]);
    half4 a3_1 = pack4_rne(ls_w1[(k0+0)*32 + 16 + m16], ls_w1[(k0+1)*32 + 16 + m16],
                           ls_w1[(k0+2)*32 + 16 + m16], ls_w1[(k0+3)*32 + 16 + m16]);
    half4 a3_2 = pack4_rne(as_w1[(k0+0)*32 + m16],      as_w1[(k0+1)*32 + m16],
                           as_w1[(k0+2)*32 + m16],      as_w1[(k0+3)*32 + m16]);
    half4 a3_3 = pack4_rne(as_w1[(k0+0)*32 + 16 + m16], as_w1[(k0+1)*32 + 16 + m16],
                           as_w1[(k0+2)*32 + 16 + m16], as_w1[(k0+3)*32 + 16 + m16]);
    half4 a4ls0 = pack4_rne(ls_w2[(k0+0)*16 + m16],      ls_w2[(k0+1)*16 + m16],
                            ls_w2[(k0+2)*16 + m16],      ls_w2[(k0+3)*16 + m16]);
    half4 a4ls1 = pack4_rne(ls_w2[(16+k0+0)*16 + m16],   ls_w2[(16+k0+1)*16 + m16],
                            ls_w2[(16+k0+2)*16 + m16],   ls_w2[(16+k0+3)*16 + m16]);
    half4 a4as0 = pack4_rne(as_w2[(k0+0)*16 + m16],      as_w2[(k0+1)*16 + m16],
                            as_w2[(k0+2)*16 + m16],      as_w2[(k0+3)*16 + m16]);
    half4 a4as1 = pack4_rne(as_w2[(16+k0+0)*16 + m16],   as_w2[(16+k0+1)*16 + m16],
                            as_w2[(16+k0+2)*16 + m16],   as_w2[(16+k0+3)*16 + m16]);
    half4 a5a = pack4_rne(
        (m16 == 0) ? ls_w3[k0 + 0] : 0.0f,
        (m16 == 0) ? ls_w3[k0 + 1] : 0.0f,
        (m16 == 0) ? ls_w3[k0 + 2] : 0.0f,
        (m16 == 0) ? ls_w3[k0 + 3] : 0.0f);
    half4 a5b = pack4_rne(
        (m16 == 1) ? as_w3[(k0+0)*2] : ((m16 == 2) ? as_w3[(k0+0)*2 + 1] : 0.0f),
        (m16 == 1) ? as_w3[(k0+1)*2] : ((m16 == 2) ? as_w3[(k0+1)*2 + 1] : 0.0f),
        (m16 == 1) ? as_w3[(k0+2)*2] : ((m16 == 2) ? as_w3[(k0+2)*2 + 1] : 0.0f),
        (m16 == 1) ? as_w3[(k0+3)*2] : ((m16 == 2) ? as_w3[(k0+3)*2 + 1] : 0.0f));

    // ---- bias fragments: C-in, reg r -> n_out = 4*g + r ----
    const int n0 = 4 * g;
    floatx4 bias1, bias2, bias3_0, bias3_1, bias3_2, bias3_3, bias4ls, bias4as, bias5;
    #pragma unroll
    for (int r = 0; r < 4; ++r) {
        bias1[r]   = le_b1[n0 + r];
        bias2[r]   = (n0 + r < 8) ? le_b2[n0 + r] : 0.0f;
        bias3_0[r] = ls_b1[n0 + r];
        bias3_1[r] = ls_b1[16 + n0 + r];
        bias3_2[r] = as_b1[n0 + r];
        bias3_3[r] = as_b1[16 + n0 + r];
        bias4ls[r] = ls_b2[n0 + r];
        bias4as[r] = as_b2[n0 + r];
        bias5[r]   = 0.0f;
    }
    if (g == 0) { bias5[0] = ls_b3[0]; bias5[1] = as_b3[0]; bias5[2] = as_b3[1]; }

    // ---- main loop: 8 tiles per wave, processed 2 at a time (independent
    //      MFMA chains A and B interleaved for ILP) ----
    const int tile0 = blockIdx.x * 32 + wave * 8;
    float* __restrict__ out2 = out + BL_TOTAL;

    for (int t = 0; t < 8; t += 2) {
        const int posA = (tile0 + t) * 16 + m16;
        const int posB = posA + 16;

        // B1 inputs: X[k][m], lane group 0 holds k=0..3, group 1 holds k=4
        float ax0 = 0.0f, ax1 = 0.0f, ax2 = 0.0f, ax3 = 0.0f;
        float bx0 = 0.0f, bx1 = 0.0f, bx2 = 0.0f, bx3 = 0.0f;
        if (g == 0) {
            ax0 = lf[posA * 5 + 0]; ax1 = lf[posA * 5 + 1];
            ax2 = lf[posA * 5 + 2]; ax3 = lf[posA * 5 + 3];
            bx0 = lf[posB * 5 + 0]; bx1 = lf[posB * 5 + 1];
            bx2 = lf[posB * 5 + 2]; bx3 = lf[posB * 5 + 3];
        } else if (g == 1) {
            ax0 = lf[posA * 5 + 4];
            bx0 = lf[posB * 5 + 4];
        }
        const int sA = ss[posA];
        const int sB = ss[posB];
        half4 evA = *reinterpret_cast<const half4*>(&embLDS[sA * 8 + (g & 1) * 4]);
        half4 evB = *reinterpret_cast<const half4*>(&embLDS[sB * 8 + (g & 1) * 4]);

        half4 b1A = pack4_rne(ax0, ax1, ax2, ax3);
        half4 b1B = pack4_rne(bx0, bx1, bx2, bx3);

        floatx4 c1A = MFMA16(a1, b1A, bias1);
        floatx4 c1B = MFMA16(a1, b1B, bias1);
        half4 h1A = relu_pack(c1A);
        half4 h1B = relu_pack(c1B);

        floatx4 c2A = MFMA16(a2, h1A, bias2);
        floatx4 c2B = MFMA16(a2, h1B, bias2);
        half4 b3A = relu_pack(c2A);
        half4 b3B = relu_pack(c2B);
        if (g >= 2) { b3A = evA; b3B = evB; }

        floatx4 c30A = MFMA16(a3_0, b3A, bias3_0);
        floatx4 c30B = MFMA16(a3_0, b3B, bias3_0);
        floatx4 c31A = MFMA16(a3_1, b3A, bias3_1);
        floatx4 c31B = MFMA16(a3_1, b3B, bias3_1);
        floatx4 c32A = MFMA16(a3_2, b3A, bias3_2);
        floatx4 c32B = MFMA16(a3_2, b3B, bias3_2);
        floatx4 c33A = MFMA16(a3_3, b3A, bias3_3);
        floatx4 c33B = MFMA16(a3_3, b3B, bias3_3);
        half4 g0A = relu_pack(c30A), g1A = relu_pack(c31A);
        half4 g2A = relu_pack(c32A), g3A = relu_pack(c33A);
        half4 g0B = relu_pack(c30B), g1B = relu_pack(c31B);
        half4 g2B = relu_pack(c32B), g3B = relu_pack(c33B);

        floatx4 clsA = MFMA16(a4ls1, g1A, MFMA16(a4ls0, g0A, bias4ls));
        floatx4 clsB = MFMA16(a4ls1, g1B, MFMA16(a4ls0, g0B, bias4ls));
        floatx4 casA = MFMA16(a4as1, g3A, MFMA16(a4as0, g2A, bias4as));
        floatx4 casB = MFMA16(a4as1, g3B, MFMA16(a4as0, g2B, bias4as));
        half4 hlsA = relu_pack(clsA), hasA = relu_pack(casA);
        half4 hlsB = relu_pack(clsB), hasB = relu_pack(casB);

        floatx4 c5A = MFMA16(a5b, hasA, MFMA16(a5a, hlsA, bias5));
        floatx4 c5B = MFMA16(a5b, hasB, MFMA16(a5a, hlsB, bias5));

        // lane group 0 holds n=0 (score), n=1 (av0), n=2 (av1) for position m16
        if (g == 0) {
            out[posA] = c5A[0];
            out[posB] = c5B[0];
            reinterpret_cast<float2*>(out2)[posA] = make_float2(c5A[1], c5A[2]);
            reinterpret_cast<float2*>(out2)[posB] = make_float2(c5B[1], c5B[2]);
        }
    }
}

extern "C" void kernel_launch(void* const* d_in, const int* in_sizes, int n_in,
                              void* d_out, int out_size, void* d_ws, size_t ws_size,
                              hipStream_t stream) {
    const float* lf    = (const float*)d_in[0];
    const int*   ss    = (const int*)  d_in[1];
    const float* le_w1 = (const float*)d_in[2];
    const float* le_b1 = (const float*)d_in[3];
    const float* le_w2 = (const float*)d_in[4];
    const float* le_b2 = (const float*)d_in[5];
    const float* emb   = (const float*)d_in[6];
    const float* ls_w1 = (const float*)d_in[7];
    const float* ls_b1 = (const float*)d_in[8];
    const float* ls_w2 = (const float*)d_in[9];
    const float* ls_b2 = (const float*)d_in[10];
    const float* ls_w3 = (const float*)d_in[11];
    const float* ls_b3 = (const float*)d_in[12];
    const float* as_w1 = (const float*)d_in[13];
    const float* as_b1 = (const float*)d_in[14];
    const float* as_w2 = (const float*)d_in[15];
    const float* as_b2 = (const float*)d_in[16];
    const float* as_w3 = (const float*)d_in[17];
    const float* as_b3 = (const float*)d_in[18];
    float* out = (float*)d_out;

    // 2048 blocks x 4 waves x 8 tiles x 16 positions = 1,048,576
    dqn_mfma<<<2048, 256, 0, stream>>>(
        lf, ss, le_w1, le_b1, le_w2, le_b2, emb,
        ls_w1, ls_b1, ls_w2, ls_b2, ls_w3, ls_b3,
        as_w1, as_b1, as_w2, as_b2, as_w3, as_b3,
        out);
}